// Round 1
// 470.879 us; speedup vs baseline: 1.0168x; 1.0168x over previous
//
#include <hip/hip_runtime.h>
#include <cstddef>

#define IN_IDX_C  128011
#define OUT_IDX_C 128012
#define PAD_ID_C  128001
#define IGNORE_C  (-100)

#define TB   1024            // planner block size
#define NW   (TB / 64)       // waves per planner block
#define MAXP 256             // max placeholders per row supported

typedef float f32x4 __attribute__((ext_vector_type(4)));

// ---------------------------------------------------------------------------
// Block-wide inclusive scan of a packed (hi16|lo16) pair via wave shfl scans
// + one LDS stage over the NW wave partials. 3 barriers total. All threads
// of the block must call. Returns inclusive value; *tot gets the block total.
// ---------------------------------------------------------------------------
__device__ __forceinline__ unsigned block_scan(unsigned x, unsigned* wp,
                                               unsigned* tot)
{
    const int tid  = threadIdx.x;
    const int lane = tid & 63;
    const int w    = tid >> 6;
    unsigned v = x;
    #pragma unroll
    for (int off = 1; off < 64; off <<= 1) {
        unsigned y = (unsigned)__shfl_up((int)v, off);
        if (lane >= off) v += y;
    }
    __syncthreads();                 // protect wp reuse from a previous call
    if (lane == 63) wp[w] = v;
    __syncthreads();
    if (w == 0) {
        unsigned pv = (lane < NW) ? wp[lane] : 0u;
        #pragma unroll
        for (int off = 1; off < NW; off <<= 1) {
            unsigned y = (unsigned)__shfl_up((int)pv, off);
            if (lane >= off) pv += y;
        }
        if (lane < NW) wp[lane] = pv;
    }
    __syncthreads();
    const unsigned base = (w > 0) ? wp[w - 1] : 0u;
    *tot = wp[NW - 1];
    return v + base;
}

// ---------------------------------------------------------------------------
// k_plan: ONE kernel for all planning + all metadata (fuses kA_counts,
// kB_row, k2_audio, k2_pad of the previous version).
// One block per batch row (overprovisioned grid; device bounds check).
//   phase 0: count placeholders in rows < b  -> global ordinal bases
//   walk 1 + scan: within-row placeholder ordinals
//   walk 2 + scan: expansion (tpn) and attention cumsums
//   walk 3: text map+meta, per-placeholder (col0,pos0,start,len) into LDS
//   fill  : cooperative audio map+meta and pad map+meta for this row
// ---------------------------------------------------------------------------
__global__ __launch_bounds__(TB) void k_plan(
    const int* __restrict__ ids, const int* __restrict__ attm,
    const int* __restrict__ labels,
    const int* __restrict__ in_starts, const int* __restrict__ out_starts,
    const int* __restrict__ pM, int BM, int BS,
    int inRows, int outRows, int nIn, int nOut,
    int* __restrict__ map, float* __restrict__ out, int D)
{
    const int M = pM[0];
    const int B = BM / M;
    const int S = BS / B;
    const int b = blockIdx.x;
    if (b >= B) return;

    const int tid = threadIdx.x;
    const int CH = (S + TB - 1) / TB;
    int s0 = tid * CH; if (s0 > S) s0 = S;
    int s1 = s0 + CH;  if (s1 > S) s1 = S;
    const int* row = ids + (size_t)b * S;

    __shared__ unsigned wp[NW];
    __shared__ int pInCol0[MAXP], pInPos0[MAXP], pInStart[MAXP], pInLen[MAXP];
    __shared__ int pOutCol0[MAXP], pOutPos0[MAXP], pOutStart[MAXP], pOutLen[MAXP];

    // ---- phase 0: global ordinal bases (placeholders in rows < b) ----
    int cip = 0, cop = 0;
    const int P = b * S;
    for (int i = tid; i < P; i += TB) {
        const int v = ids[i];
        cip += (v == IN_IDX_C);
        cop += (v == OUT_IDX_C);
    }
    unsigned tot0;
    block_scan(((unsigned)cip << 16) | (unsigned)cop, wp, &tot0);
    const int oinB = (int)(tot0 >> 16);
    const int oouB = (int)(tot0 & 0xffffu);

    // ---- walk 1: within-row placeholder ordinals ----
    int ci = 0, co = 0;
    for (int s = s0; s < s1; ++s) {
        const int v = row[s];
        ci += (v == IN_IDX_C);
        co += (v == OUT_IDX_C);
    }
    unsigned tot1;
    const unsigned pk1 = ((unsigned)ci << 16) | (unsigned)co;
    const unsigned ex1 = block_scan(pk1, wp, &tot1) - pk1;   // exclusive
    const int eci = (int)(ex1 >> 16), eco = (int)(ex1 & 0xffffu);
    const int rowIn = (int)(tot1 >> 16), rowOut = (int)(tot1 & 0xffffu);

    // ---- walk 2: expansion + attention cumsums ----
    int pin = oinB + eci, pou = oouB + eco;
    int tp = 0, at = 0;
    for (int s = s0; s < s1; ++s) {
        const int v = row[s];
        if (v == IN_IDX_C) {
            const int st = in_starts[pin];
            const int en = (pin + 1 < nIn) ? in_starts[pin + 1] : inRows;
            tp += en - st; at += en - st; ++pin;
        } else if (v == OUT_IDX_C) {
            const int st = out_starts[pou];
            const int en = (pou + 1 < nOut) ? out_starts[pou + 1] : outRows;
            tp += en - st; at += en - st; ++pou;
        } else {
            tp += 1;
            at += attm[(size_t)b * S + s];
        }
    }
    unsigned tot2;
    const unsigned pk2 = ((unsigned)tp << 16) | (unsigned)at;
    const unsigned ex2 = block_scan(pk2, wp, &tot2) - pk2;   // exclusive
    const int total = (int)(tot2 >> 16);
    const int shift = M - total;

    // ---- walk 3: text map+meta; placeholder tables into LDS ----
    int col  = shift + (int)(ex2 >> 16);
    int acum = (int)(ex2 & 0xffffu);
    pin = oinB + eci; pou = oouB + eco;
    float* meta = out + (size_t)BM * D;
    for (int s = s0; s < s1; ++s) {
        const int v = row[s];
        if (v == IN_IDX_C) {
            const int st = in_starts[pin];
            const int en = (pin + 1 < nIn) ? in_starts[pin + 1] : inRows;
            const int len = en - st;
            const int li = pin - oinB;
            if (li < MAXP) {
                pInCol0[li] = col; pInPos0[li] = acum;
                pInStart[li] = st; pInLen[li] = len;
            }
            col += len; acum += len; ++pin;
        } else if (v == OUT_IDX_C) {
            const int st = out_starts[pou];
            const int en = (pou + 1 < nOut) ? out_starts[pou + 1] : outRows;
            const int len = en - st;
            const int li = pou - oouB;
            if (li < MAXP) {
                pOutCol0[li] = col; pOutPos0[li] = acum;
                pOutStart[li] = st; pOutLen[li] = len;
            }
            col += len; acum += len; ++pou;
        } else {
            const int a   = attm[(size_t)b * S + s];
            const int lab = labels[(size_t)b * S + s];
            const size_t idx = (size_t)b * M + col;
            map[idx] = s;
            meta[idx]                  = (float)a;
            meta[(size_t)BM     + idx] = (float)lab;
            meta[(size_t)BM * 2 + idx] = (a == 0) ? 1.f : (float)(acum + a - 1);
            meta[(size_t)BM * 3 + idx] = (float)v;
            meta[(size_t)BM * 4 + idx] = 0.f;
            meta[(size_t)BM * 5 + idx] = 0.f;
            meta[(size_t)BM * 6 + idx] = 0.f;
            col += 1; acum += a;
        }
    }
    __syncthreads();

    // ---- cooperative audio fill (was k2_audio) ----
    const int nI = rowIn < MAXP ? rowIn : MAXP;
    for (int k = 0; k < nI; ++k) {
        const int c0 = pInCol0[k], p0 = pInPos0[k];
        const int st = pInStart[k], len = pInLen[k];
        for (int j = tid; j < len; j += TB) {
            const size_t idx = (size_t)b * M + c0 + j;
            map[idx] = S + st + j;
            meta[idx]                  = 1.f;
            meta[(size_t)BM     + idx] = (float)IGNORE_C;
            meta[(size_t)BM * 2 + idx] = (float)(p0 + j);
            meta[(size_t)BM * 3 + idx] = (float)IN_IDX_C;
            meta[(size_t)BM * 4 + idx] = 1.f;
            meta[(size_t)BM * 5 + idx] = 1.f;
            meta[(size_t)BM * 6 + idx] = 0.f;
        }
    }
    const int nO = rowOut < MAXP ? rowOut : MAXP;
    for (int k = 0; k < nO; ++k) {
        const int c0 = pOutCol0[k], p0 = pOutPos0[k];
        const int st = pOutStart[k], len = pOutLen[k];
        for (int j = tid; j < len; j += TB) {
            const size_t idx = (size_t)b * M + c0 + j;
            map[idx] = S + inRows + st + j;
            meta[idx]                  = 1.f;
            meta[(size_t)BM     + idx] = (float)IGNORE_C;
            meta[(size_t)BM * 2 + idx] = (float)(p0 + j);
            meta[(size_t)BM * 3 + idx] = (float)OUT_IDX_C;
            meta[(size_t)BM * 4 + idx] = 0.f;
            meta[(size_t)BM * 5 + idx] = 0.f;
            meta[(size_t)BM * 6 + idx] = 1.f;
        }
    }
    // ---- pad fill (was k2_pad) ----
    for (int m = tid; m < shift; m += TB) {
        const size_t idx = (size_t)b * M + m;
        map[idx] = -1;
        meta[idx]                  = 0.f;
        meta[(size_t)BM     + idx] = (float)IGNORE_C;
        meta[(size_t)BM * 2 + idx] = 1.f;
        meta[(size_t)BM * 3 + idx] = (float)PAD_ID_C;
        meta[(size_t)BM * 4 + idx] = 0.f;
        meta[(size_t)BM * 5 + idx] = 0.f;
        meta[(size_t)BM * 6 + idx] = 0.f;
    }
}

// ---------------------------------------------------------------------------
// k_copy: one block per merged column; float4 gather-copy of D floats with
// nontemporal stores (output is never re-read; keep L2/L3 for the read-once
// inputs). Carries ~536 MB of the ~540 MB total traffic.
// ---------------------------------------------------------------------------
__global__ __launch_bounds__(256) void k_copy(
    const float* __restrict__ audio_in, const float* __restrict__ audio_out,
    const float* __restrict__ inputs_embeds, const int* __restrict__ pM,
    int BM, int BS, int inRows, int D,
    const int* __restrict__ map, float* __restrict__ out)
{
    const int bm = blockIdx.x;
    const int v = map[bm];
    f32x4* dst = (f32x4*)(out + (size_t)bm * D);
    const int nq = D >> 2;
    if (v < 0) {
        const f32x4 z = {0.f, 0.f, 0.f, 0.f};
        for (int i = threadIdx.x; i < nq; i += blockDim.x)
            __builtin_nontemporal_store(z, &dst[i]);
        return;
    }
    const int M = pM[0];
    const int B = BM / M;
    const int S = BS / B;
    const float* src;
    if (v < S) {
        const int b = bm / M;
        src = inputs_embeds + ((size_t)b * S + v) * (size_t)D;
    } else if (v < S + inRows) {
        src = audio_in + (size_t)(v - S) * D;
    } else {
        src = audio_out + (size_t)(v - S - inRows) * D;
    }
    const f32x4* s4 = (const f32x4*)src;
    for (int i = threadIdx.x; i < nq; i += blockDim.x)
        __builtin_nontemporal_store(s4[i], &dst[i]);
}

// ---------------------------------------------------------------------------
extern "C" void kernel_launch(void* const* d_in, const int* in_sizes, int n_inputs,
                              void* d_out, int out_size, void* d_ws, size_t ws_size,
                              hipStream_t stream) {
    (void)n_inputs; (void)ws_size;
    const float* audio_in      = (const float*)d_in[0];
    const float* audio_out     = (const float*)d_in[1];
    const float* inputs_embeds = (const float*)d_in[2];
    const int* in_starts  = (const int*)d_in[3];
    const int* out_starts = (const int*)d_in[4];
    const int* ids        = (const int*)d_in[5];
    const int* attm       = (const int*)d_in[6];
    const int* labels     = (const int*)d_in[7];
    const int* pM         = (const int*)d_in[8];   // max_token_num (device scalar)

    const int nIn     = in_sizes[3];
    const int nOut    = in_sizes[4];
    const int BS      = in_sizes[5];               // B*S
    const int D       = in_sizes[2] / BS;          // embed dim
    const int inRows  = in_sizes[0] / D;
    const int outRows = in_sizes[1] / D;
    const int BM      = out_size / (D + 7);        // B*M

    int* map = (int*)d_ws;                         // [BM]
    float* out = (float*)d_out;

    // B unknown on host (M is a device scalar): overprovision, bounds-check.
    hipLaunchKernelGGL(k_plan, dim3(2048), dim3(TB), 0, stream,
        ids, attm, labels, in_starts, out_starts, pM, BM, BS,
        inRows, outRows, nIn, nOut, map, out, D);

    hipLaunchKernelGGL(k_copy, dim3(BM), dim3(256), 0, stream,
        audio_in, audio_out, inputs_embeds, pM, BM, BS, inRows, D, map, out);
}

// Round 3
// 448.499 us; speedup vs baseline: 1.0676x; 1.0499x over previous
//
#include <hip/hip_runtime.h>
#include <cstddef>

#define IN_IDX_C  128011
#define OUT_IDX_C 128012
#define PAD_ID_C  128001
#define IGNORE_C  (-100)

#define TB   1024            // planner block size
#define NW   (TB / 64)       // waves per planner block
#define MAXP 256             // max placeholders per row supported

typedef float f32x4 __attribute__((ext_vector_type(4)));

// ---------------------------------------------------------------------------
// Block-wide inclusive scan of a packed (hi16|lo16) pair via wave shfl scans
// + one LDS stage over the NW wave partials. All threads must call.
// Returns inclusive value; *tot gets the block total.
// ---------------------------------------------------------------------------
__device__ __forceinline__ unsigned block_scan(unsigned x, unsigned* wp,
                                               unsigned* tot)
{
    const int tid  = threadIdx.x;
    const int lane = tid & 63;
    const int w    = tid >> 6;
    unsigned v = x;
    #pragma unroll
    for (int off = 1; off < 64; off <<= 1) {
        unsigned y = (unsigned)__shfl_up((int)v, off);
        if (lane >= off) v += y;
    }
    __syncthreads();                 // protect wp reuse from a previous call
    if (lane == 63) wp[w] = v;
    __syncthreads();
    if (w == 0) {
        unsigned pv = (lane < NW) ? wp[lane] : 0u;
        #pragma unroll
        for (int off = 1; off < NW; off <<= 1) {
            unsigned y = (unsigned)__shfl_up((int)pv, off);
            if (lane >= off) pv += y;
        }
        if (lane < NW) wp[lane] = pv;
    }
    __syncthreads();
    const unsigned base = (w > 0) ? wp[w - 1] : 0u;
    *tot = wp[NW - 1];
    return v + base;
}

// ---------------------------------------------------------------------------
// k_plan: all planning + all metadata in one kernel.
// Grid of 64 blocks (B | gcd(BS,BM) = 64 guarantees B <= 64); each block
// loops over rows b = blockIdx.x, blockIdx.x + 64, ...
//   phase 0: count placeholders in rows < b  -> global ordinal bases
//   walk 1 + scan: within-row placeholder ordinals
//   walk 2 + scan: expansion (tpn) and attention cumsums
//   walk 3: text map+meta, per-placeholder (col0,pos0,start,len) into LDS
//   fill  : cooperative audio map+meta and pad map+meta for this row
// ---------------------------------------------------------------------------
__global__ __launch_bounds__(TB) void k_plan(
    const int* __restrict__ ids, const int* __restrict__ attm,
    const int* __restrict__ labels,
    const int* __restrict__ in_starts, const int* __restrict__ out_starts,
    const int* __restrict__ pM, int BM, int BS,
    int inRows, int outRows, int nIn, int nOut,
    int* __restrict__ map, float* __restrict__ out, int D)
{
    const int M = pM[0];
    const int B = BM / M;
    const int S = BS / B;
    const int tid = threadIdx.x;

    __shared__ unsigned wp[NW];
    __shared__ int pInCol0[MAXP], pInPos0[MAXP], pInStart[MAXP], pInLen[MAXP];
    __shared__ int pOutCol0[MAXP], pOutPos0[MAXP], pOutStart[MAXP], pOutLen[MAXP];

    float* meta = out + (size_t)BM * D;

    for (int b = blockIdx.x; b < B; b += (int)gridDim.x) {
        const int CH = (S + TB - 1) / TB;
        int s0 = tid * CH; if (s0 > S) s0 = S;
        int s1 = s0 + CH;  if (s1 > S) s1 = S;
        const int* row = ids + (size_t)b * S;

        // ---- phase 0: global ordinal bases (placeholders in rows < b) ----
        int cip = 0, cop = 0;
        const int P = b * S;
        for (int i = tid; i < P; i += TB) {
            const int v = ids[i];
            cip += (v == IN_IDX_C);
            cop += (v == OUT_IDX_C);
        }
        unsigned tot0;
        block_scan(((unsigned)cip << 16) | (unsigned)cop, wp, &tot0);
        const int oinB = (int)(tot0 >> 16);
        const int oouB = (int)(tot0 & 0xffffu);

        // ---- walk 1: within-row placeholder ordinals ----
        int ci = 0, co = 0;
        for (int s = s0; s < s1; ++s) {
            const int v = row[s];
            ci += (v == IN_IDX_C);
            co += (v == OUT_IDX_C);
        }
        unsigned tot1;
        const unsigned pk1 = ((unsigned)ci << 16) | (unsigned)co;
        const unsigned ex1 = block_scan(pk1, wp, &tot1) - pk1;   // exclusive
        const int eci = (int)(ex1 >> 16), eco = (int)(ex1 & 0xffffu);
        const int rowIn = (int)(tot1 >> 16), rowOut = (int)(tot1 & 0xffffu);

        // ---- walk 2: expansion + attention cumsums ----
        int pin = oinB + eci, pou = oouB + eco;
        int tp = 0, at = 0;
        for (int s = s0; s < s1; ++s) {
            const int v = row[s];
            if (v == IN_IDX_C) {
                const int st = in_starts[pin];
                const int en = (pin + 1 < nIn) ? in_starts[pin + 1] : inRows;
                tp += en - st; at += en - st; ++pin;
            } else if (v == OUT_IDX_C) {
                const int st = out_starts[pou];
                const int en = (pou + 1 < nOut) ? out_starts[pou + 1] : outRows;
                tp += en - st; at += en - st; ++pou;
            } else {
                tp += 1;
                at += attm[(size_t)b * S + s];
            }
        }
        unsigned tot2;
        const unsigned pk2 = ((unsigned)tp << 16) | (unsigned)at;
        const unsigned ex2 = block_scan(pk2, wp, &tot2) - pk2;   // exclusive
        const int total = (int)(tot2 >> 16);
        const int shift = M - total;

        // ---- walk 3: text map+meta; placeholder tables into LDS ----
        int col  = shift + (int)(ex2 >> 16);
        int acum = (int)(ex2 & 0xffffu);
        pin = oinB + eci; pou = oouB + eco;
        for (int s = s0; s < s1; ++s) {
            const int v = row[s];
            if (v == IN_IDX_C) {
                const int st = in_starts[pin];
                const int en = (pin + 1 < nIn) ? in_starts[pin + 1] : inRows;
                const int len = en - st;
                const int li = pin - oinB;
                if (li < MAXP) {
                    pInCol0[li] = col; pInPos0[li] = acum;
                    pInStart[li] = st; pInLen[li] = len;
                }
                col += len; acum += len; ++pin;
            } else if (v == OUT_IDX_C) {
                const int st = out_starts[pou];
                const int en = (pou + 1 < nOut) ? out_starts[pou + 1] : outRows;
                const int len = en - st;
                const int li = pou - oouB;
                if (li < MAXP) {
                    pOutCol0[li] = col; pOutPos0[li] = acum;
                    pOutStart[li] = st; pOutLen[li] = len;
                }
                col += len; acum += len; ++pou;
            } else {
                const int a   = attm[(size_t)b * S + s];
                const int lab = labels[(size_t)b * S + s];
                const size_t idx = (size_t)b * M + col;
                map[idx] = s;
                meta[idx]                  = (float)a;
                meta[(size_t)BM     + idx] = (float)lab;
                meta[(size_t)BM * 2 + idx] = (a == 0) ? 1.f : (float)(acum + a - 1);
                meta[(size_t)BM * 3 + idx] = (float)v;
                meta[(size_t)BM * 4 + idx] = 0.f;
                meta[(size_t)BM * 5 + idx] = 0.f;
                meta[(size_t)BM * 6 + idx] = 0.f;
                col += 1; acum += a;
            }
        }
        __syncthreads();

        // ---- cooperative audio fill ----
        const int nI = rowIn < MAXP ? rowIn : MAXP;
        for (int k = 0; k < nI; ++k) {
            const int c0 = pInCol0[k], p0 = pInPos0[k];
            const int st = pInStart[k], len = pInLen[k];
            for (int j = tid; j < len; j += TB) {
                const size_t idx = (size_t)b * M + c0 + j;
                map[idx] = S + st + j;
                meta[idx]                  = 1.f;
                meta[(size_t)BM     + idx] = (float)IGNORE_C;
                meta[(size_t)BM * 2 + idx] = (float)(p0 + j);
                meta[(size_t)BM * 3 + idx] = (float)IN_IDX_C;
                meta[(size_t)BM * 4 + idx] = 1.f;
                meta[(size_t)BM * 5 + idx] = 1.f;
                meta[(size_t)BM * 6 + idx] = 0.f;
            }
        }
        const int nO = rowOut < MAXP ? rowOut : MAXP;
        for (int k = 0; k < nO; ++k) {
            const int c0 = pOutCol0[k], p0 = pOutPos0[k];
            const int st = pOutStart[k], len = pOutLen[k];
            for (int j = tid; j < len; j += TB) {
                const size_t idx = (size_t)b * M + c0 + j;
                map[idx] = S + inRows + st + j;
                meta[idx]                  = 1.f;
                meta[(size_t)BM     + idx] = (float)IGNORE_C;
                meta[(size_t)BM * 2 + idx] = (float)(p0 + j);
                meta[(size_t)BM * 3 + idx] = (float)OUT_IDX_C;
                meta[(size_t)BM * 4 + idx] = 0.f;
                meta[(size_t)BM * 5 + idx] = 0.f;
                meta[(size_t)BM * 6 + idx] = 1.f;
            }
        }
        // ---- pad fill ----
        for (int m = tid; m < shift; m += TB) {
            const size_t idx = (size_t)b * M + m;
            map[idx] = -1;
            meta[idx]                  = 0.f;
            meta[(size_t)BM     + idx] = (float)IGNORE_C;
            meta[(size_t)BM * 2 + idx] = 1.f;
            meta[(size_t)BM * 3 + idx] = (float)PAD_ID_C;
            meta[(size_t)BM * 4 + idx] = 0.f;
            meta[(size_t)BM * 5 + idx] = 0.f;
            meta[(size_t)BM * 6 + idx] = 0.f;
        }
        __syncthreads();   // LDS tables reused by next row iteration
    }
}

// ---------------------------------------------------------------------------
// k_copy: one block per merged column; float4 gather-copy of D floats.
// Nontemporal loads AND stores: every byte is touched exactly once, keep
// L2/L3 out of the way. Carries ~533 MB of the ~540 MB total traffic.
// ---------------------------------------------------------------------------
__global__ __launch_bounds__(256) void k_copy(
    const float* __restrict__ audio_in, const float* __restrict__ audio_out,
    const float* __restrict__ inputs_embeds, const int* __restrict__ pM,
    int BM, int BS, int inRows, int D,
    const int* __restrict__ map, float* __restrict__ out)
{
    const int bm = blockIdx.x;
    const int v = map[bm];
    f32x4* dst = (f32x4*)(out + (size_t)bm * D);
    const int nq = D >> 2;
    if (v < 0) {
        const f32x4 z = {0.f, 0.f, 0.f, 0.f};
        for (int i = threadIdx.x; i < nq; i += blockDim.x)
            __builtin_nontemporal_store(z, &dst[i]);
        return;
    }
    const int M = pM[0];
    const int B = BM / M;
    const int S = BS / B;
    const float* src;
    if (v < S) {
        const int b = bm / M;
        src = inputs_embeds + ((size_t)b * S + v) * (size_t)D;
    } else if (v < S + inRows) {
        src = audio_in + (size_t)(v - S) * D;
    } else {
        src = audio_out + (size_t)(v - S - inRows) * D;
    }
    const f32x4* s4 = (const f32x4*)src;
    for (int i = threadIdx.x; i < nq; i += blockDim.x) {
        const f32x4 x = __builtin_nontemporal_load(&s4[i]);
        __builtin_nontemporal_store(x, &dst[i]);
    }
}

// ---------------------------------------------------------------------------
extern "C" void kernel_launch(void* const* d_in, const int* in_sizes, int n_inputs,
                              void* d_out, int out_size, void* d_ws, size_t ws_size,
                              hipStream_t stream) {
    (void)n_inputs; (void)ws_size;
    const float* audio_in      = (const float*)d_in[0];
    const float* audio_out     = (const float*)d_in[1];
    const float* inputs_embeds = (const float*)d_in[2];
    const int* in_starts  = (const int*)d_in[3];
    const int* out_starts = (const int*)d_in[4];
    const int* ids        = (const int*)d_in[5];
    const int* attm       = (const int*)d_in[6];
    const int* labels     = (const int*)d_in[7];
    const int* pM         = (const int*)d_in[8];   // max_token_num (device scalar)

    const int nIn     = in_sizes[3];
    const int nOut    = in_sizes[4];
    const int BS      = in_sizes[5];               // B*S
    const int D       = in_sizes[2] / BS;          // embed dim
    const int inRows  = in_sizes[0] / D;
    const int outRows = in_sizes[1] / D;
    const int BM      = out_size / (D + 7);        // B*M

    int* map   = (int*)d_ws;                       // [BM]
    float* out = (float*)d_out;

    // B divides gcd(BS, BM); 64 blocks cover any feasible B (loop inside).
    hipLaunchKernelGGL(k_plan, dim3(64), dim3(TB), 0, stream,
        ids, attm, labels, in_starts, out_starts, pM, BM, BS,
        inRows, outRows, nIn, nOut, map, out, D);

    hipLaunchKernelGGL(k_copy, dim3(BM), dim3(256), 0, stream,
        audio_in, audio_out, inputs_embeds, pM, BM, BS, inRows, D, map, out);
}